// Round 11
// baseline (194.510 us; speedup 1.0000x reference)
//
#include <hip/hip_runtime.h>
#include <hip/hip_bf16.h>

typedef __attribute__((ext_vector_type(8))) short short8;
typedef __attribute__((ext_vector_type(4))) short s16x4;
typedef __attribute__((ext_vector_type(4))) float f32x4;
typedef unsigned short u16;

// round-to-nearest-even fp32 -> bf16
__device__ inline u16 f2bf(float f) {
    union { float f; unsigned u; } x{f};
    unsigned r = (x.u + 0x7fff + ((x.u >> 16) & 1)) >> 16;
    return (u16)r;
}

// pack two fp32 -> packed bf16 pair (round-half-up via +0x8000, then v_perm)
__device__ inline unsigned pkbf(float hi, float lo) {
    unsigned a = __builtin_bit_cast(unsigned, hi) + 0x8000u;
    unsigned b = __builtin_bit_cast(unsigned, lo) + 0x8000u;
    return __builtin_amdgcn_perm(a, b, 0x07060302u);
}

__device__ inline float bflo(unsigned w) {
    return __builtin_bit_cast(float, w << 16);
}
__device__ inline float bfhi(unsigned w) {
    return __builtin_bit_cast(float, w & 0xffff0000u);
}

// async 16B global -> LDS (wave-uniform base + lane*16 layout)
__device__ inline void glds16(const u16* g, u16* l) {
    __builtin_amdgcn_global_load_lds(
        (const __attribute__((address_space(1))) void*)g,
        (__attribute__((address_space(3))) void*)l, 16, 0, 0);
}

// ---------------- fused prep: cvt x -> bf16 | transpose w_in | w_out --------
__global__ __launch_bounds__(256) void prep(const float* __restrict__ x,
                                            const float* __restrict__ w_in,
                                            const float* __restrict__ w_out,
                                            u16* __restrict__ Xb,
                                            u16* __restrict__ WtIn,
                                            u16* __restrict__ WtOut) {
    __shared__ float tile[32][33];
    int bx = blockIdx.x, tid = threadIdx.x;
    if (bx < 4096) {
        int i = (bx * 256 + tid) * 4;
        float4 v = *(const float4*)&x[i];
        uint2 o;
        o.x = (unsigned)f2bf(v.x) | ((unsigned)f2bf(v.y) << 16);
        o.y = (unsigned)f2bf(v.z) | ((unsigned)f2bf(v.w) << 16);
        *(uint2*)&Xb[i] = o;
        return;
    }
    const float* W; u16* Wt; int K, N, n0, k0;
    if (bx < 7168) {
        int b2 = bx - 4096;                 // w_in: K=1024, N=3072
        W = w_in; Wt = WtIn; K = 1024; N = 3072;
        n0 = (b2 % 96) * 32; k0 = (b2 / 96) * 32;
    } else {
        int b3 = bx - 7168;                 // w_out: K=1024, N=1024
        W = w_out; Wt = WtOut; K = 1024; N = 1024;
        n0 = (b3 & 31) * 32; k0 = (b3 >> 5) * 32;
    }
    int tx = tid & 31, ty = tid >> 5;
    for (int i = 0; i < 32; i += 8)
        tile[ty + i][tx] = W[(size_t)(k0 + ty + i) * N + n0 + tx];
    __syncthreads();
    for (int i = 0; i < 32; i += 8)
        Wt[(size_t)(n0 + ty + i) * K + k0 + tx] = f2bf(tile[tx][ty + i]);
}

// ---------------- transpose V slice of qkv -> Vt[b,h,dh,S] bf16 -------------
__global__ __launch_bounds__(256) void transpose_v(const u16* __restrict__ qkv,
                                                   u16* __restrict__ VT) {
    __shared__ u16 t[32][33];
    int s0 = blockIdx.x * 32, d0 = blockIdx.y * 32, bh = blockIdx.z;
    int b = bh >> 4, h = bh & 15;
    int tx = threadIdx.x, ty = threadIdx.y; // block (32,8)
    const u16* Vp = qkv + (size_t)(b * 2048) * 3072 + 2048 + h * 64;
    for (int i = 0; i < 32; i += 8)
        t[ty + i][tx] = Vp[(size_t)(s0 + ty + i) * 3072 + d0 + tx];
    __syncthreads();
    u16* Vr = VT + (size_t)bh * 64 * 2048;
    for (int i = 0; i < 32; i += 8)
        Vr[(size_t)(d0 + ty + i) * 2048 + s0 + tx] = t[tx][ty + i];
}

// ---------------- GEMM: C[M][N] = A[M][K] @ Bt[N][K]^T + bias ---------------
#define BM 128
#define BN 128
#define BK 64
__global__ __launch_bounds__(256) void gemm_bt(const u16* __restrict__ A,
                                               const u16* __restrict__ Bt,
                                               const float* __restrict__ bias,
                                               void* __restrict__ C,
                                               int M, int N, int K, int c_is_f32,
                                               int qcols, float qscale) {
    __shared__ u16 smem[2 * BM * BK + 2048];
    u16* As = smem;
    u16* Bs = smem + BM * BK;

    int tid = threadIdx.x;
    int wave = tid >> 6, lane = tid & 63;
    int quad = lane >> 4, l16 = lane & 15;
    int wm = (wave >> 1) * 64, wn = (wave & 1) * 64;

    int nm = M / BM, nn = N / BN;
    const int GM = 8;
    int per_group = GM * nn;
    int group = blockIdx.x / per_group;
    int rem = blockIdx.x % per_group;
    int first_m = group * GM;
    int gsz = (nm - first_m < GM) ? (nm - first_m) : GM;
    int m0 = (first_m + rem % gsz) * BM;
    int n0 = (rem / gsz) * BN;

    f32x4 acc[4][4] = {};

    for (int k0 = 0; k0 < K; k0 += BK) {
        __syncthreads();
        for (int i = 0; i < 4; i++) {
            int c = tid + i * 256;
            int r = c >> 3, cc = c & 7;
            int gsrc = (cc ^ (r & 7)) * 8;          // XOR swizzle
            glds16(&A[(size_t)(m0 + r) * K + k0 + gsrc], As + c * 8);
            glds16(&Bt[(size_t)(n0 + r) * K + k0 + gsrc], Bs + c * 8);
        }
        __syncthreads();
        for (int ks = 0; ks < 2; ks++) {
            short8 af[4], bf[4];
            for (int i = 0; i < 4; i++) {
                int row = wm + i * 16 + l16;
                int slot = (ks * 4 + quad) ^ (row & 7);
                af[i] = *(short8*)&As[row * BK + slot * 8];
            }
            for (int j = 0; j < 4; j++) {
                int row = wn + j * 16 + l16;
                int slot = (ks * 4 + quad) ^ (row & 7);
                bf[j] = *(short8*)&Bs[row * BK + slot * 8];
            }
            for (int i = 0; i < 4; i++)
                for (int j = 0; j < 4; j++)
                    acc[i][j] = __builtin_amdgcn_mfma_f32_16x16x32_bf16(
                        af[i], bf[j], acc[i][j], 0, 0, 0);
        }
    }

    if (c_is_f32) {
        for (int i = 0; i < 4; i++)
            for (int j = 0; j < 4; j++) {
                int col = n0 + wn + j * 16 + l16;
                float bv = bias ? bias[col] : 0.f;
                for (int r = 0; r < 4; r++) {
                    int row = m0 + wm + i * 16 + quad * 4 + r;
                    ((float*)C)[(size_t)row * N + col] = acc[i][j][r] + bv;
                }
            }
    } else {
        __syncthreads();
        u16 (*buf)[136] = (u16(*)[136])smem;
        for (int i = 0; i < 4; i++)
            for (int j = 0; j < 4; j++) {
                int col = wn + j * 16 + l16;
                float bv = bias ? bias[n0 + col] : 0.f;
                float scl = (n0 + col < qcols) ? qscale : 1.f;
                for (int r = 0; r < 4; r++)
                    buf[wm + i * 16 + quad * 4 + r][col] =
                        f2bf((acc[i][j][r] + bv) * scl);
            }
        __syncthreads();
        u16* Cb = (u16*)C;
        for (int it = 0; it < 8; it++) {
            int c = tid + it * 256;
            int row = c >> 4, k8 = c & 15;
            uint4 v = *(uint4*)&buf[row][k8 * 8];
            *(uint4*)&Cb[(size_t)(m0 + row) * N + n0 + k8 * 8] = v;
        }
    }
}

// ---------------- flash attention (causal), k-split + 32 rows/wave ----------
// 256 blocks x 512 threads, 1 block/CU. Block (p, bh, half): processes 256-row
// Q-tiles qt=7-p then qt=p, staging only k-tiles with kt%2==half: exactly 18
// tiles per block. Each wave owns 32 q-rows (2 Q-frags) so every K/V LDS
// fragment read is shared across 2 MFMA chains — halves the CU-shared LDS
// pipe traffic vs 16 rows/wave, and the f=0/1 chains supply ILP. Partial
// (unnormalized) O goes to Opart[half] in bf16 + row-sums to lpart[half];
// a combine kernel finishes softmax normalization. Valid because the no-max
// softmax makes k-tile contributions order-independent sums.
// LESSON (r8): never 2 staging blocks/CU. LESSON (r10): indep chains help.
__global__ __launch_bounds__(512, 2) void attn_kernel(const u16* __restrict__ qkv,
                                                      const u16* __restrict__ VT,
                                                      u16* __restrict__ Opart,
                                                      float* __restrict__ lpart) {
    const int S = 2048, D = 1024, stride = 3072;
    int idx = blockIdx.x;                 // 256 blocks
    int half = idx & 1;
    int bh = (idx >> 1) & 31;
    int p = idx >> 6;                     // 0..3
    int qtb[2] = {7 - p, p};              // 256-row q-tiles
    int b = bh >> 4, h = bh & 15;
    int tid = threadIdx.x;
    int wave = tid >> 6, lane = tid & 63;
    int quad = lane >> 4, l16 = lane & 15;

    __shared__ u16 Klds[2][64 * 64];      // slot (r,cc) holds chunk (r, cc^(r&7))
    __shared__ u16 Vlds[2][64 * 64];
    __shared__ u16 Obuf[8][32][72];       // per-wave output repack

    const u16* Qp = qkv + (size_t)(b * S) * stride + h * 64;
    const u16* Kp = Qp + D;
    const u16* Vtp = VT + (size_t)bh * 64 * S;

    short8 qf[2][2][2];                   // [phase][frag][k-half]
    for (int ph = 0; ph < 2; ph++)
        for (int f = 0; f < 2; f++) {
            int qrow = qtb[ph] * 256 + wave * 32 + f * 16 + l16;
            qf[ph][f][0] = *(const short8*)&Qp[(size_t)qrow * stride + quad * 8];
            qf[ph][f][1] = *(const short8*)&Qp[(size_t)qrow * stride + 32 + quad * 8];
        }

    int n0 = 2 * qtb[0] + 2;
    int total = n0 + 2 * qtb[1] + 2;      // always 18

    auto stage = [&](int kt, int bsel) {
        for (int i = 0; i < 2; i++) {
            int c = tid + i * 512;        // 1024? no: K tile = 512 chunks
            if (i == 0) {
                int r = tid >> 3, cc = tid & 7;
                int gsrc = (cc ^ (r & 7)) * 8;
                glds16(&Kp[(size_t)(kt * 64 + r) * stride + gsrc], &Klds[bsel][tid * 8]);
            } else {
                int r = tid >> 3, cc = tid & 7;
                int gsrc = (cc ^ (r & 7)) * 8;
                glds16(&Vtp[(size_t)r * S + kt * 64 + gsrc], &Vlds[bsel][tid * 8]);
            }
            (void)c;
        }
    };

    stage(half, 0);

    f32x4 O[2][4] = {};
    float lsum[2] = {};

    for (int it = 0; it < total; it++) {
        int ph = (it >= n0) ? 1 : 0;
        int j = ph ? it - n0 : it;
        int qt = qtb[ph];
        int kt = 2 * j + half;
        int cur = it & 1;
        __syncthreads();                  // drains DMA for this tile
        if (it + 1 < total) {
            int it2 = it + 1;
            int j2 = (it2 >= n0) ? it2 - n0 : it2;
            stage(2 * j2 + half, cur ^ 1);
        }

        // K fragments (A-operand), shared by both q-frag chains
        short8 kf[4][2];
        for (int nb = 0; nb < 4; nb++) {
            int r = nb * 16 + l16;
            kf[nb][0] = *(short8*)&Klds[cur][r * 64 + ((0 + quad) ^ (r & 7)) * 8];
            kf[nb][1] = *(short8*)&Klds[cur][r * 64 + ((4 + quad) ^ (r & 7)) * 8];
        }
        // S^T per chain: lane q=l16, k=nb*16+quad*4+r (Q pre-scaled)
        f32x4 st[2][4];
        for (int f = 0; f < 2; f++)
            for (int nb = 0; nb < 4; nb++) {
                f32x4 t = {};
                t = __builtin_amdgcn_mfma_f32_16x16x32_bf16(kf[nb][0], qf[ph][f][0], t, 0, 0, 0);
                t = __builtin_amdgcn_mfma_f32_16x16x32_bf16(kf[nb][1], qf[ph][f][1], t, 0, 0, 0);
                st[f][nb] = t;
            }

        if (kt >= 4 * qt) {               // boundary tiles (last 2 per half)
            for (int f = 0; f < 2; f++) {
                int qabs = qt * 256 + wave * 32 + f * 16 + l16;
                for (int nb = 0; nb < 4; nb++) {
                    int kb = kt * 64 + nb * 16 + quad * 4;
                    for (int r = 0; r < 4; r++) {
                        float e = __builtin_amdgcn_exp2f(st[f][nb][r]);
                        st[f][nb][r] = (kb + r <= qabs) ? e : 0.f;
                    }
                }
            }
        } else {
            for (int f = 0; f < 2; f++)
                for (int nb = 0; nb < 4; nb++)
                    for (int r = 0; r < 4; r++)
                        st[f][nb][r] = __builtin_amdgcn_exp2f(st[f][nb][r]);
        }

        // partial sums + pack P per chain
        s16x4 pf[2][4];
        for (int f = 0; f < 2; f++)
            for (int nb = 0; nb < 4; nb++) {
                lsum[f] += (st[f][nb][0] + st[f][nb][1]) +
                           (st[f][nb][2] + st[f][nb][3]);
                uint2 pk;
                pk.x = pkbf(st[f][nb][1], st[f][nb][0]);
                pk.y = pkbf(st[f][nb][3], st[f][nb][2]);
                pf[f][nb] = __builtin_bit_cast(s16x4, pk);
            }

        // V fragments shared across chains; PV via 16x16x16
        for (int db = 0; db < 4; db++) {
            int rr = db * 16 + l16;
            s16x4 vf[4];
            for (int kc = 0; kc < 4; kc++) {
                int g = kc * 2 + (quad >> 1);
                int slot = g ^ (rr & 7);
                vf[kc] = *(s16x4*)&Vlds[cur][rr * 64 + slot * 8 + (quad & 1) * 4];
            }
            for (int f = 0; f < 2; f++)
                for (int kc = 0; kc < 4; kc++)
                    O[f][db] = __builtin_amdgcn_mfma_f32_16x16x16bf16_1k(
                        pf[f][kc], vf[kc], O[f][db], 0, 0, 0);
        }

        // phase epilogue: store UNNORMALIZED partial O (bf16) + row sums
        if (it == n0 - 1 || it == total - 1) {
            for (int f = 0; f < 2; f++) {
                float v = lsum[f];
                v += __shfl_xor(v, 16);
                v += __shfl_xor(v, 32);   // full partial row sum at lane q=l16
                if (quad == 0) {
                    int s = qt * 256 + wave * 32 + f * 16 + l16;
                    lpart[half * 65536 + bh * 2048 + s] = v;
                }
                for (int db = 0; db < 4; db++)
                    for (int r = 0; r < 4; r++)
                        Obuf[wave][f * 16 + quad * 4 + r][db * 16 + l16] =
                            f2bf(O[f][db][r]);
            }
            __asm__ volatile("s_waitcnt lgkmcnt(0)" ::: "memory");
            for (int i = 0; i < 4; i++) {
                int c = i * 64 + lane;    // 256 chunks of 16B per wave
                int row = c >> 3, cc = c & 7;
                uint4 vv = *(uint4*)&Obuf[wave][row][cc * 8];
                int grow = qt * 256 + wave * 32 + row;
                *(uint4*)&Opart[(size_t)half * 4096 * 1024 +
                                (size_t)(b * S + grow) * D + h * 64 + cc * 8] = vv;
            }
            for (int f = 0; f < 2; f++) {
                for (int db = 0; db < 4; db++)
                    O[f][db] = (f32x4){0.f, 0.f, 0.f, 0.f};
                lsum[f] = 0.f;
            }
        }
    }
}

// ---------------- combine halves: attnb = (O0+O1)/(l0+l1), bf16 -------------
__global__ __launch_bounds__(128) void combine(const u16* __restrict__ Opart,
                                               const float* __restrict__ lpart,
                                               u16* __restrict__ attnb) {
    int g = blockIdx.x;                   // 4096 rows
    int t = threadIdx.x;                  // 128 threads x 8 cols
    int col = t * 8;
    int h = col >> 6;
    int b = g >> 11, s = g & 2047;
    int li = (b * 16 + h) * 2048 + s;
    float rinv = 1.f / (lpart[li] + lpart[65536 + li]);
    uint4 A = *(const uint4*)&Opart[(size_t)g * 1024 + col];
    uint4 B = *(const uint4*)&Opart[(size_t)4096 * 1024 + (size_t)g * 1024 + col];
    unsigned aw[4] = {A.x, A.y, A.z, A.w};
    unsigned bw[4] = {B.x, B.y, B.z, B.w};
    uint4 R;
    unsigned rw[4];
    for (int i = 0; i < 4; i++) {
        float lo = (bflo(aw[i]) + bflo(bw[i])) * rinv;
        float hi = (bfhi(aw[i]) + bfhi(bw[i])) * rinv;
        rw[i] = pkbf(hi, lo);
    }
    R.x = rw[0]; R.y = rw[1]; R.z = rw[2]; R.w = rw[3];
    *(uint4*)&attnb[(size_t)g * 1024 + col] = R;
}

// ---------------------------------------------------------------------------
extern "C" void kernel_launch(void* const* d_in, const int* in_sizes, int n_in,
                              void* d_out, int out_size, void* d_ws, size_t ws_size,
                              hipStream_t stream) {
    const float* x     = (const float*)d_in[0];
    const float* w_in  = (const float*)d_in[1];
    const float* b_in  = (const float*)d_in[2];
    const float* w_out = (const float*)d_in[3];
    const float* b_out = (const float*)d_in[4];

    const int Bsz = 2, S = 2048, D = 1024, H = 16;
    const int M = Bsz * S;
    const int N1 = 3 * D;
    const float sc = 0.125f * 1.44269504f;  // 1/sqrt(64) * log2(e)

    u16* ws    = (u16*)d_ws;
    u16* Xb    = ws;
    u16* WtIn  = Xb + (size_t)M * D;
    u16* WtOut = WtIn + (size_t)N1 * D;
    u16* qkvb  = WtOut + (size_t)D * D;
    u16* attnb = qkvb + (size_t)M * N1;
    u16* Vt    = Xb;                       // alias: Xb dead once gemm1 ran
    // partials: Opart[2][4096][1024] bf16 = 16 MB lives in d_out (overwritten
    // by gemm2 afterwards); lpart[2][32][2048] fp32 in dead WtIn region.
    u16*   Opart = (u16*)d_out;
    float* lpart = (float*)WtIn;           // WtIn dead after gemm1

    prep<<<8192, 256, 0, stream>>>(x, w_in, w_out, Xb, WtIn, WtOut);
    gemm_bt<<<(M / BM) * (N1 / BN), 256, 0, stream>>>(Xb, WtIn, b_in, qkvb,
                                                      M, N1, D, 0, D, sc);
    transpose_v<<<dim3(S / 32, 2, Bsz * H), dim3(32, 8), 0, stream>>>(qkvb, Vt);
    attn_kernel<<<256, 512, 0, stream>>>(qkvb, Vt, Opart, lpart);
    combine<<<4096, 128, 0, stream>>>(Opart, lpart, attnb);
    gemm_bt<<<(M / BM) * (D / BN), 256, 0, stream>>>(attnb, WtOut, b_out, d_out,
                                                     M, D, D, 1, 0, 1.f);
}